// Round 6
// baseline (7550.763 us; speedup 1.0000x reference)
//
#include <hip/hip_runtime.h>
#include <hip/hip_bf16.h>
#include <hip/hip_fp16.h>

#define NN 100000
#define EE 3200000
#define FF 128
#define F2 256
#define VV 8
#define LL 3
#define EPSV 1e-5f
#define SRCBITS 17
#define SRCMASK 0x1FFFF
#define CSH 9          // coarse bucket = dst>>9 (512 nodes)
#define NCRS 196       // ceil(100000/512)
#define CCHUNK 16      // 64B flush
#define FSH 5          // fine bucket = dst>>5 (32 nodes)
#define NFB 3125       // 100000/32 exactly
#define FCHUNK 32      // 128B flush

static inline int idiv(int a, int b){ return (a + b - 1) / b; }

// ---------- degree ----------
__global__ void k_deg(const int* __restrict__ dst, int* __restrict__ edeg){
  int stride = gridDim.x * 256;
  for (int e = blockIdx.x * 256 + threadIdx.x; e < EE; e += stride)
    atomicAdd(&edeg[dst[e]], 1);
}

__global__ void k_dinv(const int* __restrict__ edeg, float* __restrict__ dinv){
  int i = blockIdx.x * 256 + threadIdx.x;
  if (i < NN) dinv[i] = rsqrtf((float)(edeg[i] + 1));
}

// ---------- fine-bucket degrees ----------
__global__ void k_bdeg(const int* __restrict__ edeg, int* __restrict__ bdeg){
  int b = blockIdx.x * 256 + threadIdx.x;
  if (b < NFB){
    const int4* p = (const int4*)(edeg + (b << FSH));
    int s = 0;
    #pragma unroll
    for (int i = 0; i < 8; ++i){
      int4 v = p[i];
      s += v.x + v.y + v.z + v.w;
    }
    bdeg[b] = s;
  }
}

// ---------- single-block scan of 3125 fine-bucket degrees ----------
__global__ void k_bscan(const int* __restrict__ bdeg, int* __restrict__ boffsF,
                        int* __restrict__ gcurF, int* __restrict__ gcurC){
  __shared__ int s[1024];
  __shared__ int carry;
  int t = threadIdx.x;
  if (t == 0) carry = 0;
  __syncthreads();
  for (int c0 = 0; c0 < NFB; c0 += 1024){
    int i = c0 + t;
    int v = (i < NFB) ? bdeg[i] : 0;
    int x = v;
    s[t] = x; __syncthreads();
    for (int d = 1; d < 1024; d <<= 1){
      int y = (t >= d) ? s[t - d] : 0;
      __syncthreads();
      x += y; s[t] = x;
      __syncthreads();
    }
    int excl = x - v + carry;
    if (i < NFB){
      boffsF[i] = excl;
      gcurF[i] = excl;
      if ((i & 15) == 0) gcurC[i >> 4] = excl;
    }
    __syncthreads();
    if (t == 1023) carry += s[1023];
    __syncthreads();
  }
  if (t == 0) boffsF[NFB] = EE;
}

// ---------- pass A: bin into coarse buckets, per-wave LDS staging, 64B flushes ----------
__launch_bounds__(256)
__global__ void k_binA(const int* __restrict__ src, const int* __restrict__ dst,
                       int* __restrict__ gcurC, unsigned int* __restrict__ binA){
  __shared__ unsigned int stg[4][NCRS][CCHUNK];
  __shared__ int cnt[4][NCRS];
  int tid = threadIdx.x, w = tid >> 6, lane = tid & 63;
  for (int b = lane; b < NCRS; b += 64) cnt[w][b] = 0;
  asm volatile("s_waitcnt lgkmcnt(0)" ::: "memory");
  int stride = gridDim.x * 256;
  int nit = (EE + stride - 1) / stride;
  int e = blockIdx.x * 256 + tid;
  int dcur = 0, scur = 0;
  bool valid = (e < EE);
  if (valid){ dcur = dst[e]; scur = src[e]; }
  for (int it = 0; it < nit; ++it){
    int en = e + stride;
    int dn = 0, sn = 0;
    bool vn2 = (it + 1 < nit) && (en < EE);
    if (vn2){ dn = dst[en]; sn = src[en]; }
    bool pending = valid;
    int cb = dcur >> CSH;
    unsigned int word = ((unsigned int)(dcur & ((1 << CSH) - 1)) << SRCBITS) | (unsigned int)scur;
    while (__any(pending ? 1 : 0)){
      if (pending){
        int p = atomicAdd(&cnt[w][cb], 1);
        if (p < CCHUNK){ stg[w][cb][p] = word; pending = false; }
      }
      asm volatile("s_waitcnt lgkmcnt(0)" ::: "memory");
      for (int b = lane; b < NCRS; b += 64){
        int c = cnt[w][b];
        if (c >= CCHUNK){
          int pos = atomicAdd(&gcurC[b], CCHUNK);
          if ((pos & 3) == 0){
            #pragma unroll
            for (int k = 0; k < CCHUNK; k += 4)
              *(uint4*)&binA[pos + k] = *(uint4*)&stg[w][b][k];
          } else {
            #pragma unroll
            for (int k = 0; k < CCHUNK; ++k) binA[pos + k] = stg[w][b][k];
          }
          cnt[w][b] = 0;
        }
      }
      asm volatile("s_waitcnt lgkmcnt(0)" ::: "memory");
    }
    e = en; dcur = dn; scur = sn; valid = vn2;
  }
  // drain partials
  asm volatile("s_waitcnt lgkmcnt(0)" ::: "memory");
  for (int b = lane; b < NCRS; b += 64){
    int c = cnt[w][b];
    if (c > 0){
      int pos = atomicAdd(&gcurC[b], c);
      for (int k = 0; k < c; ++k) binA[pos + k] = stg[w][b][k];
    }
  }
}

// ---------- pass B: coarse -> fine (32-node) buckets, 128B flushes ----------
__launch_bounds__(256)
__global__ void k_binB(const unsigned int* __restrict__ binA, const int* __restrict__ boffsF,
                       int* __restrict__ gcurF, unsigned int* __restrict__ binF){
  __shared__ unsigned int stg[4][16][FCHUNK];
  __shared__ int cnt[4][16];
  int tid = threadIdx.x, w = tid >> 6, lane = tid & 63;
  int cb = blockIdx.x >> 1;
  int half = blockIdx.x & 1;
  int fb0 = cb << 4;
  int e0c = boffsF[fb0];
  int e1c = boffsF[min(fb0 + 16, NFB)];
  int mid = e0c + ((e1c - e0c) >> 1);
  int lo = half ? mid : e0c;
  int hi = half ? e1c : mid;
  if (lane < 16) cnt[w][lane] = 0;
  asm volatile("s_waitcnt lgkmcnt(0)" ::: "memory");
  int nit = (hi - lo + 255) / 256;
  int e = lo + tid;
  unsigned int wcur = 0;
  bool valid = (e < hi);
  if (valid) wcur = binA[e];
  for (int it = 0; it < nit; ++it){
    int en = e + 256;
    unsigned int wn = 0;
    bool vn2 = (it + 1 < nit) && (en < hi);
    if (vn2) wn = binA[en];
    bool pending = valid;
    int dl9 = (int)(wcur >> SRCBITS);
    int fbl = dl9 >> FSH;                      // 0..15
    unsigned int word = ((unsigned int)(dl9 & 31) << SRCBITS) | (wcur & SRCMASK);
    while (__any(pending ? 1 : 0)){
      if (pending){
        int p = atomicAdd(&cnt[w][fbl], 1);
        if (p < FCHUNK){ stg[w][fbl][p] = word; pending = false; }
      }
      asm volatile("s_waitcnt lgkmcnt(0)" ::: "memory");
      if (lane < 16){
        int c = cnt[w][lane];
        if (c >= FCHUNK){
          int pos = atomicAdd(&gcurF[fb0 + lane], FCHUNK);
          if ((pos & 3) == 0){
            #pragma unroll
            for (int k = 0; k < FCHUNK; k += 4)
              *(uint4*)&binF[pos + k] = *(uint4*)&stg[w][lane][k];
          } else {
            #pragma unroll
            for (int k = 0; k < FCHUNK; ++k) binF[pos + k] = stg[w][lane][k];
          }
          cnt[w][lane] = 0;
        }
      }
      asm volatile("s_waitcnt lgkmcnt(0)" ::: "memory");
    }
    e = en; wcur = wn; valid = vn2;
  }
  asm volatile("s_waitcnt lgkmcnt(0)" ::: "memory");
  if (lane < 16){
    int c = cnt[w][lane];
    if (c > 0){
      int pos = atomicAdd(&gcurF[fb0 + lane], c);
      for (int k = 0; k < c; ++k) binF[pos + k] = stg[w][lane][k];
    }
  }
}

// ---------- mask dtype detect: 1 = bool(1B), 0 = int32 ----------
__global__ void k_maskdetect(const unsigned char* __restrict__ m, int* __restrict__ flag){
  int any = 0;
  for (int t = threadIdx.x; t < 4096; t += 256)
    if ((t & 3) && m[t]) any = 1;
  if (any) atomicOr(flag, 1);
}

// ---------- hlb[n] = fp16( (relu(bn(in[n]))@W + (sum_v vn)@W) * dinv[n] ) ----------
// 32 rows x 128 cols per tile; thread: 4 rows x 4 cols (Ws float4 reused 4x)
__launch_bounds__(256)
__global__ void k_matmul(const float* __restrict__ in, const float* __restrict__ W,
                         const float* __restrict__ vn, const float* __restrict__ dinv,
                         const float* __restrict__ ss, int hasbn,
                         uint2* __restrict__ hlb){
  __shared__ float Ws[FF * FF];     // 64 KB
  __shared__ float As[32 * FF];     // 16 KB
  __shared__ float vs[FF];
  __shared__ float rv[FF];
  __shared__ float scs[FF], shs[FF];
  int tid = threadIdx.x;
  for (int t = tid; t < FF * FF; t += 256) Ws[t] = W[t];
  if (tid < FF){
    float s = 0.f;
    for (int v = 0; v < VV; ++v) s += vn[v * FF + tid];
    vs[tid] = s;
    scs[tid] = hasbn ? ss[tid] : 1.0f;
    shs[tid] = hasbn ? ss[FF + tid] : 0.0f;
  }
  __syncthreads();
  if (tid < FF){
    float a = 0.f;
    for (int k = 0; k < FF; ++k) a += vs[k] * Ws[k * FF + tid];
    rv[tid] = a;
  }
  __syncthreads();
  int g = tid >> 5;                 // 0..7 row group
  int c = tid & 31;                 // col quad
  float4 rvv = ((const float4*)rv)[c];
  for (int base = blockIdx.x * 32; base < NN; base += gridDim.x * 32){
    const float4* in4 = (const float4*)(in + (size_t)base * FF);
    for (int i = tid; i < 32 * 32; i += 256){
      float4 vv = in4[i];
      if (hasbn){
        int cq = (i & 31) * 4;
        vv.x = fmaxf(fmaf(vv.x, scs[cq + 0], shs[cq + 0]), 0.f);
        vv.y = fmaxf(fmaf(vv.y, scs[cq + 1], shs[cq + 1]), 0.f);
        vv.z = fmaxf(fmaf(vv.z, scs[cq + 2], shs[cq + 2]), 0.f);
        vv.w = fmaxf(fmaf(vv.w, scs[cq + 3], shs[cq + 3]), 0.f);
      }
      ((float4*)As)[i] = vv;
    }
    __syncthreads();
    float4 a0 = rvv, a1 = rvv, a2 = rvv, a3 = rvv;
    #pragma unroll 4
    for (int k = 0; k < FF; ++k){
      float4 wv = ((const float4*)Ws)[k * 32 + c];
      float x0 = As[(g +  0) * FF + k];
      float x1 = As[(g +  8) * FF + k];
      float x2 = As[(g + 16) * FF + k];
      float x3 = As[(g + 24) * FF + k];
      a0.x += x0 * wv.x; a0.y += x0 * wv.y; a0.z += x0 * wv.z; a0.w += x0 * wv.w;
      a1.x += x1 * wv.x; a1.y += x1 * wv.y; a1.z += x1 * wv.z; a1.w += x1 * wv.w;
      a2.x += x2 * wv.x; a2.y += x2 * wv.y; a2.z += x2 * wv.z; a2.w += x2 * wv.w;
      a3.x += x3 * wv.x; a3.y += x3 * wv.y; a3.z += x3 * wv.z; a3.w += x3 * wv.w;
    }
    #pragma unroll
    for (int rr = 0; rr < 4; ++rr){
      float4 a = (rr == 0) ? a0 : (rr == 1) ? a1 : (rr == 2) ? a2 : a3;
      int r = base + g + 8 * rr;
      float d = dinv[r];
      __half2 h01 = __floats2half2_rn(a.x * d, a.y * d);
      __half2 h23 = __floats2half2_rn(a.z * d, a.w * d);
      uint2 pk;
      pk.x = *reinterpret_cast<unsigned int*>(&h01);
      pk.y = *reinterpret_cast<unsigned int*>(&h23);
      hlb[(size_t)r * 32 + c] = pk;
    }
    __syncthreads();
  }
}

// ---------- bucket gather: block per fine bucket, wave-per-edge, LDS f32 accum ----------
__launch_bounds__(256)
__global__ void k_gatherb(const unsigned int* __restrict__ hlb, const float* __restrict__ dinv,
                          const int* __restrict__ boffsF, const unsigned int* __restrict__ binF,
                          float2* __restrict__ agg2, float* __restrict__ stats){
  __shared__ float acc[32 * FF];    // 16 KB
  int tid = threadIdx.x, w = tid >> 6, lane = tid & 63;
  int fb = blockIdx.x;
  for (int i = tid; i < 32 * FF; i += 256) acc[i] = 0.f;
  __syncthreads();
  int e0 = boffsF[fb], e1 = boffsF[fb + 1];
  for (int e = e0 + w; e < e1; e += 4){
    unsigned int word = binF[e];
    int dl = (int)(word >> SRCBITS);
    int s  = (int)(word & SRCMASK);
    unsigned int u = hlb[(size_t)s * 64 + lane];
    float2 f = __half22float2(*reinterpret_cast<__half2*>(&u));
    atomicAdd(&acc[dl * FF + 2 * lane], f.x);
    atomicAdd(&acc[dl * FF + 2 * lane + 1], f.y);
  }
  __syncthreads();
  float s0 = 0.f, s1 = 0.f, q0 = 0.f, q1 = 0.f;
  for (int nl = w * 8; nl < w * 8 + 8; ++nl){
    int n = (fb << FSH) + nl;
    unsigned int u = hlb[(size_t)n * 64 + lane];
    float2 f = __half22float2(*reinterpret_cast<__half2*>(&u));
    float dv = dinv[n];
    float v0 = (acc[nl * FF + 2 * lane] + f.x) * dv;
    float v1 = (acc[nl * FF + 2 * lane + 1] + f.y) * dv;
    agg2[(size_t)n * 64 + lane] = make_float2(v0, v1);
    s0 += v0; s1 += v1; q0 += v0 * v0; q1 += v1 * v1;
  }
  __syncthreads();
  float4* red = (float4*)acc;
  red[tid] = make_float4(s0, s1, q0, q1);
  __syncthreads();
  if (w == 0){
    float4 a = red[lane], b = red[lane + 64], c = red[lane + 128], d = red[lane + 192];
    a.x += b.x + c.x + d.x; a.y += b.y + c.y + d.y;
    a.z += b.z + c.z + d.z; a.w += b.w + c.w + d.w;
    atomicAdd(&stats[2 * lane], a.x);
    atomicAdd(&stats[2 * lane + 1], a.y);
    atomicAdd(&stats[FF + 2 * lane], a.z);
    atomicAdd(&stats[FF + 2 * lane + 1], a.w);
  }
}

// ---------- stats -> scale/shift ----------
__global__ void k_bnfin(const float* __restrict__ stats, const float* __restrict__ g,
                        const float* __restrict__ b, float* __restrict__ ss){
  int j = threadIdx.x;   // 128
  float mean = stats[j] * (1.0f / NN);
  float var  = stats[FF + j] * (1.0f / NN) - mean * mean;
  float sc = rsqrtf(var + EPSV) * g[j];
  ss[j] = sc;
  ss[FF + j] = b[j] - mean * sc;
}

// ---------- BN finalize + apply (final layer, no relu) ----------
__launch_bounds__(256)
__global__ void k_bnapply(float4* __restrict__ h, const float* __restrict__ stats,
                          const float* __restrict__ g, const float* __restrict__ b){
  __shared__ float ss[2 * FF];
  int tid = threadIdx.x;
  if (tid < FF){
    float mean = stats[tid] * (1.0f / NN);
    float var  = stats[FF + tid] * (1.0f / NN) - mean * mean;
    float sc = rsqrtf(var + EPSV) * g[tid];
    ss[tid] = sc;
    ss[FF + tid] = b[tid] - mean * sc;
  }
  __syncthreads();
  int n4 = NN * FF / 4;
  int stride = gridDim.x * 256;
  for (int i = blockIdx.x * 256 + tid; i < n4; i += stride){
    int c = (i & 31) * 4;
    float4 v = h[i];
    float4 sc = *(const float4*)&ss[c];
    float4 sh = *(const float4*)&ss[FF + c];
    v.x = v.x * sc.x + sh.x;
    v.y = v.y * sc.y + sh.y;
    v.z = v.z * sc.z + sh.z;
    v.w = v.w * sc.w + sh.w;
    h[i] = v;
  }
}

// ---------- pooled[v] = sum_{n: mask[v][n]} relu(bn(emb[n])) ----------
__global__ void k_pool(const float* __restrict__ emb, const unsigned char* __restrict__ m8,
                       const int* __restrict__ m32, const int* __restrict__ flag,
                       const float* __restrict__ ss, int hasbn,
                       float* __restrict__ pooled){
  int isb = *flag;
  int tid = blockIdx.x * 256 + threadIdx.x;
  int j = tid & 127;
  int r = tid >> 7;
  int rs = (gridDim.x * 256) >> 7;
  float sc = hasbn ? ss[j] : 1.0f;
  float sh = hasbn ? ss[FF + j] : 0.0f;
  float acc[VV];
  #pragma unroll
  for (int v = 0; v < VV; ++v) acc[v] = 0.f;
  for (; r < NN; r += rs){
    float xv = emb[r * FF + j];
    xv = fmaf(xv, sc, sh);
    if (hasbn) xv = fmaxf(xv, 0.f);
    #pragma unroll
    for (int v = 0; v < VV; ++v){
      int mv = isb ? (int)m8[v * NN + r] : m32[v * NN + r];
      if (mv) acc[v] += xv;
    }
  }
  #pragma unroll
  for (int v = 0; v < VV; ++v) atomicAdd(&pooled[v * FF + j], acc[v]);
}

// ---------- per-VN MLP ----------
__device__ __forceinline__ float blockSum(float x, float* red, int tid){
  red[tid] = x; __syncthreads();
  #pragma unroll
  for (int s = 128; s >= 1; s >>= 1){
    if (tid < s) red[tid] += red[tid + s];
    __syncthreads();
  }
  float r = red[0];
  __syncthreads();
  return r;
}

__launch_bounds__(256)
__global__ void k_vnmlp(const float* __restrict__ pooled, const float* __restrict__ vnin,
                        const float* __restrict__ W1, const float* __restrict__ b1,
                        const float* __restrict__ g1, const float* __restrict__ bb1,
                        const float* __restrict__ W2, const float* __restrict__ b2,
                        const float* __restrict__ g2, const float* __restrict__ bb2,
                        float* __restrict__ vnout){
  int v = blockIdx.x;
  int tid = threadIdx.x;
  __shared__ float tmp_s[FF];
  __shared__ float h1_s[F2];
  __shared__ float red[256];
  if (tid < FF) tmp_s[tid] = pooled[v * FF + tid] + vnin[v * FF + tid];
  __syncthreads();
  const float* W1v = W1 + (size_t)v * FF * F2;
  float acc = b1[v * F2 + tid];
  for (int k = 0; k < FF; ++k) acc += tmp_s[k] * W1v[k * F2 + tid];
  acc = fmaxf(acc, 0.f);
  float sum = blockSum(acc, red, tid);
  float sq  = blockSum(acc * acc, red, tid);
  float mean = sum * (1.f / F2);
  float var  = sq * (1.f / F2) - mean * mean;
  float y = (acc - mean) * rsqrtf(var + EPSV) * g1[v * F2 + tid] + bb1[v * F2 + tid];
  h1_s[tid] = y;
  __syncthreads();
  const float* W2v = W2 + (size_t)v * F2 * FF;
  float h2 = 0.f;
  if (tid < FF){
    float a2 = b2[v * FF + tid];
    for (int k = 0; k < F2; ++k) a2 += h1_s[k] * W2v[k * FF + tid];
    h2 = fmaxf(a2, 0.f);
  }
  float sum2 = blockSum((tid < FF) ? h2 : 0.f, red, tid);
  float sq2  = blockSum((tid < FF) ? h2 * h2 : 0.f, red, tid);
  float mean2 = sum2 * (1.f / FF);
  float var2  = sq2 * (1.f / FF) - mean2 * mean2;
  if (tid < FF)
    vnout[v * FF + tid] = (h2 - mean2) * rsqrtf(var2 + EPSV) * g2[v * FF + tid]
                          + bb2[v * FF + tid];
}

extern "C" void kernel_launch(void* const* d_in, const int* in_sizes, int n_in,
                              void* d_out, int out_size, void* d_ws, size_t ws_size,
                              hipStream_t stream){
  const float* x        = (const float*)d_in[0];
  const int*   ei       = (const int*)d_in[1];
  const unsigned char* vmask8 = (const unsigned char*)d_in[2];
  const int*   vmask32  = (const int*)d_in[2];
  const float* Wc       = (const float*)d_in[3];
  const float* bn_g     = (const float*)d_in[5];
  const float* bn_b     = (const float*)d_in[6];
  const float* vn_embed = (const float*)d_in[7];
  const float* mlp_W1   = (const float*)d_in[8];
  const float* mlp_b1   = (const float*)d_in[9];
  const float* ln1_g    = (const float*)d_in[10];
  const float* ln1_b    = (const float*)d_in[11];
  const float* mlp_W2   = (const float*)d_in[12];
  const float* mlp_b2   = (const float*)d_in[13];
  const float* ln2_g    = (const float*)d_in[14];
  const float* ln2_b    = (const float*)d_in[15];
  float* out = (float*)d_out;

  unsigned int* hlb  = (unsigned int*)d_ws;              // N*64 u32 (fp16x2) = 25.6MB
  unsigned int* binA = hlb;                              // alias: dead before 1st matmul
  float* bufB    = (float*)(hlb + (size_t)NN * 64);      // N*F f32
  unsigned int* binF = (unsigned int*)(bufB + (size_t)NN * FF);  // E u32 (persistent)
  int*   edeg    = (int*)(binF + EE);                    // N
  int*   bdeg    = edeg + NN;                            // NFB
  int*   boffsF  = bdeg + NFB;                           // NFB+1
  int*   gcurF   = boffsF + NFB + 1;                     // NFB
  int*   gcurC   = gcurF + NFB;                          // NCRS
  float* dinv    = (float*)(gcurC + NCRS);               // N
  float* stats   = dinv + NN;                            // 2F
  float* ssA     = stats + 2 * FF;                       // 2F
  float* ssB     = ssA + 2 * FF;                         // 2F
  float* pooled  = ssB + 2 * FF;                         // V*F
  float* vnA     = pooled + VV * FF;                     // V*F
  float* vnB     = vnA + VV * FF;                        // V*F
  int*   mflag   = (int*)(vnB + VV * FF);                // 1

  const int* esrc = ei;
  const int* edst = ei + EE;

  // ----- CSR-bucket build -----
  hipMemsetAsync(edeg, 0, NN * sizeof(int), stream);
  k_deg<<<1024, 256, 0, stream>>>(edst, edeg);
  k_dinv<<<idiv(NN, 256), 256, 0, stream>>>(edeg, dinv);
  k_bdeg<<<idiv(NFB, 256), 256, 0, stream>>>(edeg, bdeg);
  k_bscan<<<1, 1024, 0, stream>>>(bdeg, boffsF, gcurF, gcurC);
  k_binA<<<128, 256, 0, stream>>>(esrc, edst, gcurC, binA);
  k_binB<<<2 * NCRS, 256, 0, stream>>>(binA, boffsF, gcurF, binF);

  hipMemsetAsync(mflag, 0, sizeof(int), stream);
  k_maskdetect<<<1, 256, 0, stream>>>(vmask8, mflag);

  const float* vncur = vn_embed;
  const float* embin = x;
  float* ssbufs[2] = {ssA, ssB};
  const float* sscur = nullptr;
  float* vnbufs[2] = {vnA, vnB};

  for (int l = 0; l < LL; ++l){
    float* agg = (l < LL - 1) ? bufB : out;
    const float* Wl = Wc + (size_t)l * FF * FF;
    int hasbn = (l > 0) ? 1 : 0;

    k_matmul<<<1024, 256, 0, stream>>>(embin, Wl, vncur, dinv, sscur, hasbn, (uint2*)hlb);

    if (l < LL - 1){
      hipMemsetAsync(pooled, 0, VV * FF * sizeof(float), stream);
      k_pool<<<1024, 256, 0, stream>>>(embin, vmask8, vmask32, mflag, sscur, hasbn, pooled);
    }

    hipMemsetAsync(stats, 0, 2 * FF * sizeof(float), stream);
    k_gatherb<<<NFB, 256, 0, stream>>>(hlb, dinv, boffsF, binF, (float2*)agg, stats);

    if (l < LL - 1){
      k_bnfin<<<1, 128, 0, stream>>>(stats, bn_g + l * FF, bn_b + l * FF, ssbufs[l]);
      k_vnmlp<<<VV, 256, 0, stream>>>(pooled, vncur,
          mlp_W1 + (size_t)l * VV * FF * F2, mlp_b1 + (size_t)l * VV * F2,
          ln1_g + (size_t)l * VV * F2, ln1_b + (size_t)l * VV * F2,
          mlp_W2 + (size_t)l * VV * F2 * FF, mlp_b2 + (size_t)l * VV * FF,
          ln2_g + (size_t)l * VV * FF, ln2_b + (size_t)l * VV * FF,
          vnbufs[l]);
      vncur = vnbufs[l];
      sscur = ssbufs[l];
      embin = agg;
    } else {
      k_bnapply<<<1024, 256, 0, stream>>>((float4*)out, stats, bn_g + l * FF, bn_b + l * FF);
    }
  }
}

// Round 7
// 1665.703 us; speedup vs baseline: 4.5331x; 4.5331x over previous
//
#include <hip/hip_runtime.h>
#include <hip/hip_bf16.h>
#include <hip/hip_fp16.h>

#define NN 100000
#define EE 3200000
#define FF 128
#define F2 256
#define VV 8
#define LL 3
#define EPSV 1e-5f
#define NB 98        // idiv(NN,1024)

static inline int idiv(int a, int b){ return (a + b - 1) / b; }

// ---------- degree count ----------
__global__ void k_deg(const int* __restrict__ dst, int* __restrict__ edeg){
  int stride = gridDim.x * 256;
  for (int e = blockIdx.x * 256 + threadIdx.x; e < EE; e += stride)
    atomicAdd(&edeg[dst[e]], 1);
}

// ---------- exclusive scan of edeg -> offs (+ dinv) ----------
__global__ void k_scanA(const int* __restrict__ edeg, int* __restrict__ offs,
                        int* __restrict__ bsum, float* __restrict__ dinv){
  __shared__ int s[1024];
  int t = threadIdx.x;
  int i = blockIdx.x * 1024 + t;
  int v = (i < NN) ? edeg[i] : 0;
  if (i < NN) dinv[i] = rsqrtf((float)(v + 1));
  int x = v;
  s[t] = x; __syncthreads();
  for (int d = 1; d < 1024; d <<= 1){
    int y = (t >= d) ? s[t - d] : 0;
    __syncthreads();
    x += y; s[t] = x;
    __syncthreads();
  }
  if (i < NN) offs[i] = x - v;
  if (t == 1023) bsum[blockIdx.x] = x;
}

__global__ void k_scanB(int* __restrict__ bsum){
  __shared__ int s[128];
  int t = threadIdx.x;
  s[t] = (t < NB) ? bsum[t] : 0;
  __syncthreads();
  if (t == 0){
    int run = 0;
    for (int k = 0; k < NB; ++k){ int tmp = s[k]; s[k] = run; run += tmp; }
  }
  __syncthreads();
  if (t < NB) bsum[t] = s[t];
}

__global__ void k_scanC(int* __restrict__ offs, const int* __restrict__ bsum,
                        int* __restrict__ cursor){
  int i = blockIdx.x * 256 + threadIdx.x;
  if (i < NN){
    int o = offs[i] + bsum[i >> 10];
    offs[i] = o;
    cursor[i] = o;
  }
  if (i == 0) offs[NN] = EE;
}

// ---------- counting-sort scatter ----------
__global__ void k_scatter(const int* __restrict__ src, const int* __restrict__ dst,
                          int* __restrict__ cursor, int* __restrict__ ssorted){
  int stride = gridDim.x * 256;
  for (int e = blockIdx.x * 256 + threadIdx.x; e < EE; e += stride){
    int d = dst[e];
    int pos = atomicAdd(&cursor[d], 1);
    ssorted[pos] = src[e];
  }
}

// ---------- mask dtype detect: 1 = bool(1B), 0 = int32 ----------
__global__ void k_maskdetect(const unsigned char* __restrict__ m, int* __restrict__ flag){
  int any = 0;
  for (int t = threadIdx.x; t < 4096; t += 256)
    if ((t & 3) && m[t]) any = 1;
  if (any) atomicOr(flag, 1);
}

// ---------- hlb[n] = fp16( (relu(bn(in[n]))@W + (sum_v vn)@W) * dinv[n] ) ----------
// 32 rows x 128 cols per tile; thread: 4 rows x 4 cols (Ws float4 reused 4x)
__launch_bounds__(256)
__global__ void k_matmul(const float* __restrict__ in, const float* __restrict__ W,
                         const float* __restrict__ vn, const float* __restrict__ dinv,
                         const float* __restrict__ ss, int hasbn,
                         uint2* __restrict__ hlb){
  __shared__ float Ws[FF * FF];     // 64 KB
  __shared__ float As[32 * FF];     // 16 KB
  __shared__ float vs[FF];
  __shared__ float rv[FF];
  __shared__ float scs[FF], shs[FF];
  int tid = threadIdx.x;
  for (int t = tid; t < FF * FF; t += 256) Ws[t] = W[t];
  if (tid < FF){
    float s = 0.f;
    for (int v = 0; v < VV; ++v) s += vn[v * FF + tid];
    vs[tid] = s;
    scs[tid] = hasbn ? ss[tid] : 1.0f;
    shs[tid] = hasbn ? ss[FF + tid] : 0.0f;
  }
  __syncthreads();
  if (tid < FF){
    float a = 0.f;
    for (int k = 0; k < FF; ++k) a += vs[k] * Ws[k * FF + tid];
    rv[tid] = a;
  }
  __syncthreads();
  int g = tid >> 5;                 // 0..7 row group
  int c = tid & 31;                 // col quad
  float4 rvv = ((const float4*)rv)[c];
  for (int base = blockIdx.x * 32; base < NN; base += gridDim.x * 32){
    const float4* in4 = (const float4*)(in + (size_t)base * FF);
    for (int i = tid; i < 32 * 32; i += 256){
      float4 vv = in4[i];
      if (hasbn){
        int cq = (i & 31) * 4;
        vv.x = fmaxf(fmaf(vv.x, scs[cq + 0], shs[cq + 0]), 0.f);
        vv.y = fmaxf(fmaf(vv.y, scs[cq + 1], shs[cq + 1]), 0.f);
        vv.z = fmaxf(fmaf(vv.z, scs[cq + 2], shs[cq + 2]), 0.f);
        vv.w = fmaxf(fmaf(vv.w, scs[cq + 3], shs[cq + 3]), 0.f);
      }
      ((float4*)As)[i] = vv;
    }
    __syncthreads();
    float4 a0 = rvv, a1 = rvv, a2 = rvv, a3 = rvv;
    #pragma unroll 4
    for (int k = 0; k < FF; ++k){
      float4 wv = ((const float4*)Ws)[k * 32 + c];
      float x0 = As[(g +  0) * FF + k];
      float x1 = As[(g +  8) * FF + k];
      float x2 = As[(g + 16) * FF + k];
      float x3 = As[(g + 24) * FF + k];
      a0.x += x0 * wv.x; a0.y += x0 * wv.y; a0.z += x0 * wv.z; a0.w += x0 * wv.w;
      a1.x += x1 * wv.x; a1.y += x1 * wv.y; a1.z += x1 * wv.z; a1.w += x1 * wv.w;
      a2.x += x2 * wv.x; a2.y += x2 * wv.y; a2.z += x2 * wv.z; a2.w += x2 * wv.w;
      a3.x += x3 * wv.x; a3.y += x3 * wv.y; a3.z += x3 * wv.z; a3.w += x3 * wv.w;
    }
    #pragma unroll
    for (int rr = 0; rr < 4; ++rr){
      float4 a = (rr == 0) ? a0 : (rr == 1) ? a1 : (rr == 2) ? a2 : a3;
      int r = base + g + 8 * rr;
      float d = dinv[r];
      __half2 h01 = __floats2half2_rn(a.x * d, a.y * d);
      __half2 h23 = __floats2half2_rn(a.z * d, a.w * d);
      uint2 pk;
      pk.x = *reinterpret_cast<unsigned int*>(&h01);
      pk.y = *reinterpret_cast<unsigned int*>(&h23);
      hlb[(size_t)r * 32 + c] = pk;
    }
    __syncthreads();
  }
}

// ---------- wave-per-node CSR gather + BN stats (register accumulation) ----------
__launch_bounds__(256)
__global__ void k_gather(const unsigned int* __restrict__ hlb, const float* __restrict__ dinv,
                         const int* __restrict__ offs, const int* __restrict__ ssorted,
                         float2* __restrict__ agg2, float* __restrict__ stats){
  int tid = threadIdx.x;
  int lane = tid & 63;
  int wid = (blockIdx.x * 256 + tid) >> 6;
  int nw = (gridDim.x * 256) >> 6;
  float s0 = 0.f, s1 = 0.f, q0 = 0.f, q1 = 0.f;
  for (int n = wid; n < NN; n += nw){
    int off0 = offs[n], off1 = offs[n + 1];
    unsigned int ps = hlb[(size_t)n * 64 + lane];   // self term (prescaled)
    float2 acc = __half22float2(*reinterpret_cast<__half2*>(&ps));
    #pragma unroll 8
    for (int e = off0; e < off1; ++e){
      unsigned int p = hlb[(size_t)ssorted[e] * 64 + lane];
      float2 f = __half22float2(*reinterpret_cast<__half2*>(&p));
      acc.x += f.x; acc.y += f.y;
    }
    float dv = dinv[n];
    float v0 = acc.x * dv, v1 = acc.y * dv;
    agg2[(size_t)n * 64 + lane] = make_float2(v0, v1);
    s0 += v0; s1 += v1; q0 += v0 * v0; q1 += v1 * v1;
  }
  __shared__ float4 red[256];
  red[tid] = make_float4(s0, s1, q0, q1);
  __syncthreads();
  if (tid < 64){
    float4 a = red[tid], b = red[tid + 64], c = red[tid + 128], d = red[tid + 192];
    a.x += b.x + c.x + d.x; a.y += b.y + c.y + d.y;
    a.z += b.z + c.z + d.z; a.w += b.w + c.w + d.w;
    atomicAdd(&stats[2 * tid], a.x);
    atomicAdd(&stats[2 * tid + 1], a.y);
    atomicAdd(&stats[FF + 2 * tid], a.z);
    atomicAdd(&stats[FF + 2 * tid + 1], a.w);
  }
}

// ---------- stats -> scale/shift ----------
__global__ void k_bnfin(const float* __restrict__ stats, const float* __restrict__ g,
                        const float* __restrict__ b, float* __restrict__ ss){
  int j = threadIdx.x;   // 128
  float mean = stats[j] * (1.0f / NN);
  float var  = stats[FF + j] * (1.0f / NN) - mean * mean;
  float sc = rsqrtf(var + EPSV) * g[j];
  ss[j] = sc;
  ss[FF + j] = b[j] - mean * sc;
}

// ---------- BN finalize + apply (final layer, no relu) ----------
__launch_bounds__(256)
__global__ void k_bnapply(float4* __restrict__ h, const float* __restrict__ stats,
                          const float* __restrict__ g, const float* __restrict__ b){
  __shared__ float ss[2 * FF];
  int tid = threadIdx.x;
  if (tid < FF){
    float mean = stats[tid] * (1.0f / NN);
    float var  = stats[FF + tid] * (1.0f / NN) - mean * mean;
    float sc = rsqrtf(var + EPSV) * g[tid];
    ss[tid] = sc;
    ss[FF + tid] = b[tid] - mean * sc;
  }
  __syncthreads();
  int n4 = NN * FF / 4;
  int stride = gridDim.x * 256;
  for (int i = blockIdx.x * 256 + tid; i < n4; i += stride){
    int c = (i & 31) * 4;
    float4 v = h[i];
    float4 sc = *(const float4*)&ss[c];
    float4 sh = *(const float4*)&ss[FF + c];
    v.x = v.x * sc.x + sh.x;
    v.y = v.y * sc.y + sh.y;
    v.z = v.z * sc.z + sh.z;
    v.w = v.w * sc.w + sh.w;
    h[i] = v;
  }
}

// ---------- pooled[v] = sum_{n: mask[v][n]} relu(bn(emb[n])) ----------
__global__ void k_pool(const float* __restrict__ emb, const unsigned char* __restrict__ m8,
                       const int* __restrict__ m32, const int* __restrict__ flag,
                       const float* __restrict__ ss, int hasbn,
                       float* __restrict__ pooled){
  int isb = *flag;
  int tid = blockIdx.x * 256 + threadIdx.x;
  int j = tid & 127;
  int r = tid >> 7;
  int rs = (gridDim.x * 256) >> 7;
  float sc = hasbn ? ss[j] : 1.0f;
  float sh = hasbn ? ss[FF + j] : 0.0f;
  float acc[VV];
  #pragma unroll
  for (int v = 0; v < VV; ++v) acc[v] = 0.f;
  for (; r < NN; r += rs){
    float xv = emb[r * FF + j];
    xv = fmaf(xv, sc, sh);
    if (hasbn) xv = fmaxf(xv, 0.f);
    #pragma unroll
    for (int v = 0; v < VV; ++v){
      int mv = isb ? (int)m8[v * NN + r] : m32[v * NN + r];
      if (mv) acc[v] += xv;
    }
  }
  #pragma unroll
  for (int v = 0; v < VV; ++v) atomicAdd(&pooled[v * FF + j], acc[v]);
}

// ---------- per-VN MLP ----------
__device__ __forceinline__ float blockSum(float x, float* red, int tid){
  red[tid] = x; __syncthreads();
  #pragma unroll
  for (int s = 128; s >= 1; s >>= 1){
    if (tid < s) red[tid] += red[tid + s];
    __syncthreads();
  }
  float r = red[0];
  __syncthreads();
  return r;
}

__launch_bounds__(256)
__global__ void k_vnmlp(const float* __restrict__ pooled, const float* __restrict__ vnin,
                        const float* __restrict__ W1, const float* __restrict__ b1,
                        const float* __restrict__ g1, const float* __restrict__ bb1,
                        const float* __restrict__ W2, const float* __restrict__ b2,
                        const float* __restrict__ g2, const float* __restrict__ bb2,
                        float* __restrict__ vnout){
  int v = blockIdx.x;
  int tid = threadIdx.x;
  __shared__ float tmp_s[FF];
  __shared__ float h1_s[F2];
  __shared__ float red[256];
  if (tid < FF) tmp_s[tid] = pooled[v * FF + tid] + vnin[v * FF + tid];
  __syncthreads();
  const float* W1v = W1 + (size_t)v * FF * F2;
  float acc = b1[v * F2 + tid];
  for (int k = 0; k < FF; ++k) acc += tmp_s[k] * W1v[k * F2 + tid];
  acc = fmaxf(acc, 0.f);
  float sum = blockSum(acc, red, tid);
  float sq  = blockSum(acc * acc, red, tid);
  float mean = sum * (1.f / F2);
  float var  = sq * (1.f / F2) - mean * mean;
  float y = (acc - mean) * rsqrtf(var + EPSV) * g1[v * F2 + tid] + bb1[v * F2 + tid];
  h1_s[tid] = y;
  __syncthreads();
  const float* W2v = W2 + (size_t)v * F2 * FF;
  float h2 = 0.f;
  if (tid < FF){
    float a2 = b2[v * FF + tid];
    for (int k = 0; k < F2; ++k) a2 += h1_s[k] * W2v[k * FF + tid];
    h2 = fmaxf(a2, 0.f);
  }
  float sum2 = blockSum((tid < FF) ? h2 : 0.f, red, tid);
  float sq2  = blockSum((tid < FF) ? h2 * h2 : 0.f, red, tid);
  float mean2 = sum2 * (1.f / FF);
  float var2  = sq2 * (1.f / FF) - mean2 * mean2;
  if (tid < FF)
    vnout[v * FF + tid] = (h2 - mean2) * rsqrtf(var2 + EPSV) * g2[v * FF + tid]
                          + bb2[v * FF + tid];
}

extern "C" void kernel_launch(void* const* d_in, const int* in_sizes, int n_in,
                              void* d_out, int out_size, void* d_ws, size_t ws_size,
                              hipStream_t stream){
  const float* x        = (const float*)d_in[0];
  const int*   ei       = (const int*)d_in[1];
  const unsigned char* vmask8 = (const unsigned char*)d_in[2];
  const int*   vmask32  = (const int*)d_in[2];
  const float* Wc       = (const float*)d_in[3];
  const float* bn_g     = (const float*)d_in[5];
  const float* bn_b     = (const float*)d_in[6];
  const float* vn_embed = (const float*)d_in[7];
  const float* mlp_W1   = (const float*)d_in[8];
  const float* mlp_b1   = (const float*)d_in[9];
  const float* ln1_g    = (const float*)d_in[10];
  const float* ln1_b    = (const float*)d_in[11];
  const float* mlp_W2   = (const float*)d_in[12];
  const float* mlp_b2   = (const float*)d_in[13];
  const float* ln2_g    = (const float*)d_in[14];
  const float* ln2_b    = (const float*)d_in[15];
  float* out = (float*)d_out;

  unsigned int* hlb = (unsigned int*)d_ws;               // N*64 u32 (fp16x2) = 25.6MB
  float* bufB    = (float*)(hlb + (size_t)NN * 64);      // N*F f32
  int*   ssorted = (int*)(bufB + (size_t)NN * FF);       // E
  int*   offs    = ssorted + EE;                         // N+1
  int*   cursor  = offs + NN + 1;                        // N
  int*   edeg    = cursor + NN;                          // N
  int*   bsum    = edeg + NN;                            // 128
  float* dinv    = (float*)(bsum + 128);                 // N
  float* stats   = dinv + NN;                            // 2F
  float* ssA     = stats + 2 * FF;                       // 2F
  float* ssB     = ssA + 2 * FF;                         // 2F
  float* pooled  = ssB + 2 * FF;                         // V*F
  float* vnA     = pooled + VV * FF;                     // V*F
  float* vnB     = vnA + VV * FF;                        // V*F
  int*   mflag   = (int*)(vnB + VV * FF);                // 1

  const int* esrc = ei;
  const int* edst = ei + EE;

  // ----- CSR build -----
  hipMemsetAsync(edeg, 0, NN * sizeof(int), stream);
  k_deg<<<1024, 256, 0, stream>>>(edst, edeg);
  k_scanA<<<NB, 1024, 0, stream>>>(edeg, offs, bsum, dinv);
  k_scanB<<<1, 128, 0, stream>>>(bsum);
  k_scanC<<<idiv(NN, 256), 256, 0, stream>>>(offs, bsum, cursor);
  k_scatter<<<2048, 256, 0, stream>>>(esrc, edst, cursor, ssorted);

  hipMemsetAsync(mflag, 0, sizeof(int), stream);
  k_maskdetect<<<1, 256, 0, stream>>>(vmask8, mflag);

  const float* vncur = vn_embed;
  const float* embin = x;
  float* ssbufs[2] = {ssA, ssB};
  const float* sscur = nullptr;
  float* vnbufs[2] = {vnA, vnB};

  for (int l = 0; l < LL; ++l){
    float* agg = (l < LL - 1) ? bufB : out;
    const float* Wl = Wc + (size_t)l * FF * FF;
    int hasbn = (l > 0) ? 1 : 0;

    k_matmul<<<1024, 256, 0, stream>>>(embin, Wl, vncur, dinv, sscur, hasbn, (uint2*)hlb);

    if (l < LL - 1){
      hipMemsetAsync(pooled, 0, VV * FF * sizeof(float), stream);
      k_pool<<<1024, 256, 0, stream>>>(embin, vmask8, vmask32, mflag, sscur, hasbn, pooled);
    }

    hipMemsetAsync(stats, 0, 2 * FF * sizeof(float), stream);
    k_gather<<<2048, 256, 0, stream>>>(hlb, dinv, offs, ssorted, (float2*)agg, stats);

    if (l < LL - 1){
      k_bnfin<<<1, 128, 0, stream>>>(stats, bn_g + l * FF, bn_b + l * FF, ssbufs[l]);
      k_vnmlp<<<VV, 256, 0, stream>>>(pooled, vncur,
          mlp_W1 + (size_t)l * VV * FF * F2, mlp_b1 + (size_t)l * VV * F2,
          ln1_g + (size_t)l * VV * F2, ln1_b + (size_t)l * VV * F2,
          mlp_W2 + (size_t)l * VV * F2 * FF, mlp_b2 + (size_t)l * VV * FF,
          ln2_g + (size_t)l * VV * FF, ln2_b + (size_t)l * VV * FF,
          vnbufs[l]);
      vncur = vnbufs[l];
      sscur = ssbufs[l];
      embin = agg;
    } else {
      k_bnapply<<<1024, 256, 0, stream>>>((float4*)out, stats, bn_g + l * FF, bn_b + l * FF);
    }
  }
}